// Round 4
// baseline (1169.119 us; speedup 1.0000x reference)
//
#include <hip/hip_runtime.h>
#include <hip/hip_bf16.h>
#include <math.h>

typedef unsigned short u16;
typedef short bf16x8 __attribute__((ext_vector_type(8)));
typedef float f32x4 __attribute__((ext_vector_type(4)));

#define LN2F 0.693147180559945f

__device__ __forceinline__ float bf2f(u16 h) {
  union { unsigned int i; float f; } v; v.i = ((unsigned int)h) << 16; return v.f;
}
__device__ __forceinline__ u16 f2bf(float f) {
  union { float f; unsigned int i; } v; v.f = f;
  unsigned int x = v.i;
  return (u16)((x + 0x7fffu + ((x >> 16) & 1u)) >> 16);
}
// shifted softplus, numerically stable, inf-safe
__device__ __forceinline__ float sspf(float v) {
  return fmaxf(v, 0.0f) + log1pf(__expf(-fabsf(v))) - LN2F;
}
// scalar load in mode dtype
template<int MODE>
__device__ __forceinline__ float ldv(const void* p, size_t i) {
  if constexpr (MODE == 0) return bf2f(((const u16*)p)[i]);
  else                     return ((const float*)p)[i];
}

// ---------------------------------------------------------------------------
// Dtype probe: bf16 N(0,1) data never has bf16-exponent >= 0xC0 (|v|>=2^64);
// f32 data misread as u16 halfwords certainly does (mantissa-garbage lows).
// flag: 0 = inputs are bf16, 1 = inputs are f32.
// ---------------------------------------------------------------------------
__global__ void probe_k(const u16* __restrict__ x, int* __restrict__ flag) {
  __shared__ int sf;
  if (threadIdx.x == 0) sf = 0;
  __syncthreads();
  int f = 0;
  for (int i = threadIdx.x; i < 4096; i += 256) {
    const unsigned e = (x[i] >> 7) & 0xFFu;
    if (e >= 0xC0u) f = 1;
  }
  if (f) atomicOr(&sf, 1);
  __syncthreads();
  if (threadIdx.x == 0) *flag = sf;
}

// ---------------------------------------------------------------------------
// MFMA GEMM: C[M,128] = epi(A[M,KD] @ B[KD,128])
// AK: 0 = A is bf16 ptr, 1 = A is f32 ptr.  PREACT: ssp on A load.
// MODE: global input dtype (weights/bias/x/u) 0=bf16 1=f32.
// EPI: 0 = f32 out, ssp(acc+bias)
//      1 = bf16 out, ssp(acc+bias)
//      3 = f32 out, out += acc + bias
//      4 = out (mode dtype) = u[col]*x[row,col] + acc + bias
// MFMA 16x16x32 bf16 layouts (HW-verified):
//   A[m=lane&15][k=(lane>>4)*8+j], B[k=(lane>>4)*8+j][n=lane&15],
//   C/D: col=lane&15, row=(lane>>4)*4+reg.
// ---------------------------------------------------------------------------
template<int KSTEPS, int AK, bool PREACT, int EPI, int MODE>
__global__ __launch_bounds__(256) void gemm_k(
    const int* __restrict__ mode,
    const void* __restrict__ A_, const void* __restrict__ Bg,
    const void* __restrict__ bias,
    float* __restrict__ outf, void* __restrict__ outb,
    const void* __restrict__ xg, const void* __restrict__ ug,
    int M)
{
  if (*mode != MODE) return;
  constexpr int KD = KSTEPS * 32;
  __shared__ u16 sB[128][KD + 8];
  const int tid = threadIdx.x;
  for (int base = tid * 8; base < 128 * KD; base += 256 * 8) {
    const int k = base >> 7, n = base & 127;   // B row-major [KD,128]
    if constexpr (MODE == 0) {
      ushort4 q0 = *(const ushort4*)((const u16*)Bg + base);
      ushort4 q1 = *(const ushort4*)((const u16*)Bg + base + 4);
      sB[n + 0][k] = q0.x; sB[n + 1][k] = q0.y; sB[n + 2][k] = q0.z; sB[n + 3][k] = q0.w;
      sB[n + 4][k] = q1.x; sB[n + 5][k] = q1.y; sB[n + 6][k] = q1.z; sB[n + 7][k] = q1.w;
    } else {
      float4 a0 = *(const float4*)((const float*)Bg + base);
      float4 a1 = *(const float4*)((const float*)Bg + base + 4);
      sB[n + 0][k] = f2bf(a0.x); sB[n + 1][k] = f2bf(a0.y);
      sB[n + 2][k] = f2bf(a0.z); sB[n + 3][k] = f2bf(a0.w);
      sB[n + 4][k] = f2bf(a1.x); sB[n + 5][k] = f2bf(a1.y);
      sB[n + 6][k] = f2bf(a1.z); sB[n + 7][k] = f2bf(a1.w);
    }
  }
  __syncthreads();

  const int lane = tid & 63, wave = tid >> 6;
  const int m16 = lane & 15, quad = lane >> 4;
  const int row_tile = blockIdx.x * 64 + wave * 16;
  int arow = row_tile + m16; if (arow >= M) arow = M - 1;  // clamp (stores masked)

  f32x4 acc[8];
#pragma unroll
  for (int t = 0; t < 8; ++t) acc[t] = (f32x4){0.f, 0.f, 0.f, 0.f};

#pragma unroll
  for (int s = 0; s < KSTEPS; ++s) {
    const int k0 = s * 32 + quad * 8;
    bf16x8 af;
    if constexpr (AK == 0) {
      const u16* ap = (const u16*)A_ + (size_t)arow * KD + k0;
      bf16x8 raw = *(const bf16x8*)ap;
      if constexpr (!PREACT) {
        af = raw;
      } else {
#pragma unroll
        for (int j = 0; j < 8; ++j) af[j] = (short)f2bf(sspf(bf2f((u16)raw[j])));
      }
    } else {
      const float* ap = (const float*)A_ + (size_t)arow * KD + k0;
      float4 lo = *(const float4*)ap;
      float4 hi = *(const float4*)(ap + 4);
      float v[8] = {lo.x, lo.y, lo.z, lo.w, hi.x, hi.y, hi.z, hi.w};
#pragma unroll
      for (int j = 0; j < 8; ++j) af[j] = (short)f2bf(PREACT ? sspf(v[j]) : v[j]);
    }
#pragma unroll
    for (int t = 0; t < 8; ++t) {
      bf16x8 bfr = *(const bf16x8*)&sB[t * 16 + m16][k0];
      acc[t] = __builtin_amdgcn_mfma_f32_16x16x32_bf16(af, bfr, acc[t], 0, 0, 0);
    }
  }

#pragma unroll
  for (int t = 0; t < 8; ++t) {
    const int col = t * 16 + m16;
    const float bv = ldv<MODE>(bias, col);
#pragma unroll
    for (int r = 0; r < 4; ++r) {
      const int ro = row_tile + quad * 4 + r;
      if (ro >= M) continue;
      const size_t off = (size_t)ro * 128 + col;
      float v = acc[t][r] + bv;
      if constexpr (EPI == 0)      outf[off] = sspf(v);
      else if constexpr (EPI == 1) ((u16*)outb)[off] = f2bf(sspf(v));
      else if constexpr (EPI == 3) outf[off] += v;
      else {
        const float o = ldv<MODE>(ug, col) * ldv<MODE>(xg, off) + v;
        if constexpr (MODE == 0) ((u16*)outb)[off] = f2bf(o);
        else                     ((float*)outb)[off] = o;
      }
    }
  }
}

// ---------------------------------------------------------------------------
// Fused edge kernel: g = rbf_tile @ Wk2f (MFMA), msg = g * xj_all[idx_j],
// in-block segment reduction over sorted idx_i, boundary atomicAdd into mb.
// ---------------------------------------------------------------------------
template<int MODE>
__global__ __launch_bounds__(256) void edge_k(
    const int* __restrict__ mode,
    const void* __restrict__ rbf, const void* __restrict__ Wk2f,
    const u16* __restrict__ xj_all, const int* __restrict__ idx_i,
    const int* __restrict__ idx_j, float* __restrict__ mb, int E)
{
  if (*mode != MODE) return;
  __shared__ u16 sW[128][72];     // Wk2f^T [n][k], KD=64
  __shared__ u16 sXj[64][132];
  __shared__ u16 sMsg[64][132];
  __shared__ int sIi[64], sIj[64];
  const int tid = threadIdx.x;
  const int e0 = blockIdx.x * 64;

  for (int base = tid * 8; base < 64 * 128; base += 2048) {
    const int k = base >> 7, n = base & 127;
    if constexpr (MODE == 0) {
      ushort4 q0 = *(const ushort4*)((const u16*)Wk2f + base);
      ushort4 q1 = *(const ushort4*)((const u16*)Wk2f + base + 4);
      sW[n + 0][k] = q0.x; sW[n + 1][k] = q0.y; sW[n + 2][k] = q0.z; sW[n + 3][k] = q0.w;
      sW[n + 4][k] = q1.x; sW[n + 5][k] = q1.y; sW[n + 6][k] = q1.z; sW[n + 7][k] = q1.w;
    } else {
      float4 a0 = *(const float4*)((const float*)Wk2f + base);
      float4 a1 = *(const float4*)((const float*)Wk2f + base + 4);
      sW[n + 0][k] = f2bf(a0.x); sW[n + 1][k] = f2bf(a0.y);
      sW[n + 2][k] = f2bf(a0.z); sW[n + 3][k] = f2bf(a0.w);
      sW[n + 4][k] = f2bf(a1.x); sW[n + 5][k] = f2bf(a1.y);
      sW[n + 6][k] = f2bf(a1.z); sW[n + 7][k] = f2bf(a1.w);
    }
  }
  if (tid < 64) {
    const int e = e0 + tid;
    sIi[tid] = (e < E) ? idx_i[e] : -1;
    sIj[tid] = (e < E) ? idx_j[e] : 0;
  }
  __syncthreads();

  {
    const int le = tid >> 4;
    const int c0 = (tid & 15) * 8;
#pragma unroll
    for (int p = 0; p < 4; ++p) {
      const int e = le + p * 16;
      const u16* src = xj_all + (size_t)sIj[e] * 128 + c0;
      ushort4 q0 = *(const ushort4*)src;
      ushort4 q1 = *(const ushort4*)(src + 4);
      *(ushort4*)&sXj[e][c0]     = q0;
      *(ushort4*)&sXj[e][c0 + 4] = q1;
    }
  }
  __syncthreads();

  const int lane = tid & 63, wave = tid >> 6;
  const int m16 = lane & 15, quad = lane >> 4;
  int erow = e0 + wave * 16 + m16; if (erow >= E) erow = E - 1;

  f32x4 acc[8];
#pragma unroll
  for (int t = 0; t < 8; ++t) acc[t] = (f32x4){0.f, 0.f, 0.f, 0.f};

#pragma unroll
  for (int s = 0; s < 2; ++s) {
    const int k0 = s * 32 + quad * 8;
    bf16x8 af;
    if constexpr (MODE == 0) {
      af = *(const bf16x8*)((const u16*)rbf + (size_t)erow * 64 + k0);
    } else {
      const float* ap = (const float*)rbf + (size_t)erow * 64 + k0;
      float4 lo = *(const float4*)ap;
      float4 hi = *(const float4*)(ap + 4);
      af[0] = f2bf(lo.x); af[1] = f2bf(lo.y); af[2] = f2bf(lo.z); af[3] = f2bf(lo.w);
      af[4] = f2bf(hi.x); af[5] = f2bf(hi.y); af[6] = f2bf(hi.z); af[7] = f2bf(hi.w);
    }
#pragma unroll
    for (int t = 0; t < 8; ++t) {
      bf16x8 bfr = *(const bf16x8*)&sW[t * 16 + m16][k0];
      acc[t] = __builtin_amdgcn_mfma_f32_16x16x32_bf16(af, bfr, acc[t], 0, 0, 0);
    }
  }

#pragma unroll
  for (int t = 0; t < 8; ++t) {
    const int col = t * 16 + m16;
#pragma unroll
    for (int r = 0; r < 4; ++r) {
      const int le = wave * 16 + quad * 4 + r;
      float xv = (e0 + le < E) ? bf2f(sXj[le][col]) : 0.f;
      sMsg[le][col] = f2bf(acc[t][r] * xv);
    }
  }
  __syncthreads();

  const int col = tid & 127;
  const int ebeg = (tid >> 7) * 32, eend = ebeg + 32;
  float sum = 0.f;
  int cur = sIi[ebeg];
  for (int le = ebeg; le < eend; ++le) {
    const int node = sIi[le];
    if (node != cur) {
      if (cur >= 0) atomicAdd(&mb[(size_t)cur * 128 + col], sum);
      sum = 0.f; cur = node;
    }
    sum += bf2f(sMsg[le][col]);
  }
  if (cur >= 0) atomicAdd(&mb[(size_t)cur * 128 + col], sum);
}

// launch one full pipeline for a given MODE
template<int MODE>
static void run_pipeline(const int* flag,
                         const void* x, const void* rbf, const void* Wk2f,
                         const void* Wi, const void* bi, const void* Wj, const void* bj,
                         const void* Wr1, const void* br1, const void* Wr2, const void* br2,
                         const void* Wf, const void* bfv, const void* uv,
                         const int* idx_i, const int* idx_j,
                         float* mb, u16* xjt, void* out,
                         int N, int E, int L, hipStream_t stream)
{
  const dim3 blk(256);
  const int gridN = (N + 63) / 64;
  const int gridE = (E + 63) / 64;
  constexpr int AX = (MODE == 0) ? 0 : 1;   // A-kind for x

  // mb = xi = ssp(ssp(x)@Wi + bi)   [f32]
  gemm_k<4, AX, true, 0, MODE><<<gridN, blk, 0, stream>>>(flag, x, Wi, bi, mb, nullptr, nullptr, nullptr, N);
  // xjt = xj_all = ssp(ssp(x)@Wj + bj)   [bf16]
  gemm_k<4, AX, true, 1, MODE><<<gridN, blk, 0, stream>>>(flag, x, Wj, bj, nullptr, xjt, nullptr, nullptr, N);
  // mb += segment_sum( (rbf@Wk2f) * xj_all[idx_j] )
  edge_k<MODE><<<gridE, blk, 0, stream>>>(flag, rbf, Wk2f, xjt, idx_i, idx_j, mb, E);
  // residual blocks (xjt reused as t1)
  const size_t WSTRIDE = 16384 * ((MODE == 0) ? 2 : 4);  // bytes per [128,128] weight
  const size_t BSTRIDE = 128 * ((MODE == 0) ? 2 : 4);
  for (int l = 0; l < L; ++l) {
    const void* w1 = (const char*)Wr1 + (size_t)l * WSTRIDE;
    const void* b1 = (const char*)br1 + (size_t)l * BSTRIDE;
    const void* w2 = (const char*)Wr2 + (size_t)l * WSTRIDE;
    const void* b2 = (const char*)br2 + (size_t)l * BSTRIDE;
    gemm_k<4, 1, true, 1, MODE><<<gridN, blk, 0, stream>>>(flag, mb, w1, b1, nullptr, xjt, nullptr, nullptr, N);
    gemm_k<4, 0, false, 3, MODE><<<gridN, blk, 0, stream>>>(flag, xjt, w2, b2, mb, nullptr, nullptr, nullptr, N);
  }
  // out = u*x + ssp(mb)@Wf + bf
  gemm_k<4, 1, true, 4, MODE><<<gridN, blk, 0, stream>>>(flag, mb, Wf, bfv, nullptr, out, x, uv, N);
}

extern "C" void kernel_launch(void* const* d_in, const int* in_sizes, int n_in,
                              void* d_out, int out_size, void* d_ws, size_t ws_size,
                              hipStream_t stream)
{
  const void* x    = d_in[0];
  const void* rbf  = d_in[1];
  const void* Wk2f = d_in[2];
  const void* Wi   = d_in[3];
  const void* bi   = d_in[4];
  const void* Wj   = d_in[5];
  const void* bj   = d_in[6];
  const void* Wr1  = d_in[7];
  const void* br1  = d_in[8];
  const void* Wr2  = d_in[9];
  const void* br2  = d_in[10];
  const void* Wf   = d_in[11];
  const void* bfv  = d_in[12];
  const void* uv   = d_in[13];
  const int* idx_i = (const int*)d_in[14];
  const int* idx_j = (const int*)d_in[15];

  const int N = in_sizes[0] / 128;
  const int E = in_sizes[14];
  const int L = in_sizes[7] / (128 * 128);

  int* flag = (int*)d_ws;
  char* wsb = (char*)d_ws + 16;
  const size_t avail = ws_size > 16 ? ws_size - 16 : 0;
  const size_t needF = (size_t)N * 512;   // mb f32
  const size_t needH = (size_t)N * 256;   // bf16 scratch (xj_all / t1)

  // bf16-mode layout
  float* mb0; u16* xjt0;
  if (avail >= needF + needH) { mb0 = (float*)wsb; xjt0 = (u16*)(wsb + needF); }
  else                        { mb0 = (float*)wsb; xjt0 = (u16*)d_out; }
  // f32-mode layout (d_out is N*128 f32 = needF bytes -> can host mb in-place)
  float* mb1; u16* xjt1;
  if (avail >= needF + needH)      { mb1 = (float*)wsb;  xjt1 = (u16*)(wsb + needF); }
  else if (avail >= needF)         { mb1 = (float*)wsb;  xjt1 = (u16*)d_out; }
  else                             { mb1 = (float*)d_out; xjt1 = (u16*)wsb; }

  probe_k<<<1, 256, 0, stream>>>((const u16*)x, flag);
  run_pipeline<0>(flag, x, rbf, Wk2f, Wi, bi, Wj, bj, Wr1, br1, Wr2, br2,
                  Wf, bfv, uv, idx_i, idx_j, mb0, xjt0, d_out, N, E, L, stream);
  run_pipeline<1>(flag, x, rbf, Wk2f, Wi, bi, Wj, bj, Wr1, br1, Wr2, br2,
                  Wf, bfv, uv, idx_i, idx_j, mb1, xjt1, d_out, N, E, L, stream);
}